// Round 6
// baseline (228.705 us; speedup 1.0000x reference)
//
#include <hip/hip_runtime.h>

#define BS 16
#define NP 500000
#define NOBJ 16
#define NSEG3 48        // NOBJ*3
#define GX 128          // blocks per scene
#define NSUB 16         // LDS sub-tables, selected by lane&15

typedef float f32x4 __attribute__((ext_vector_type(4)));  // native vec for nontemporal store

// ws word layout (slots written unconditionally every call -> no init pass):
//   slotmin : [0, 98304)         BS*GX*48   per-block min keys
//   slotmax : [98304, 196608)               per-block max keys
//   slotmask: [196608, 198656)   BS*GX      per-block presence bitmask
//   ctr     : [198656, 198672)   BS         ticket counter (NEVER reset: each call
//             adds exactly GX per scene; 128 | 2^32 so exactly one block per scene
//             per call draws (ticket & 127)==127, for ANY starting/poison value)
#define WS_SMAX 98304
#define WS_SMSK 196608
#define WS_CTR  198656

// Order-preserving float -> uint key (min/max over keys == min/max over floats)
__device__ __forceinline__ unsigned fkey(float f) {
    unsigned u = __float_as_uint(f);
    return (u & 0x80000000u) ? ~u : (u | 0x80000000u);
}
__device__ __forceinline__ float keyf(unsigned k) {
    unsigned u = (k & 0x80000000u) ? (k ^ 0x80000000u) : ~k;
    return __uint_as_float(u);
}

// Single fused kernel: stream pc+tag once; speculative obj_batch = tag + b*16;
// per-block bbox partials via LDS atomics (16 sub-tables, ~2 lanes/bank);
// last block per scene (ticket pattern) reduces partials + writes keypoints.
__global__ __launch_bounds__(256) void kmain(const float* __restrict__ pc,
                                             const int* __restrict__ tag,
                                             unsigned* __restrict__ ws,
                                             float* __restrict__ out) {
    __shared__ unsigned lmin[NSUB * NSEG3], lmax[NSUB * NSEG3];
    __shared__ unsigned lmask;
    __shared__ unsigned ticket_s;
    __shared__ unsigned smin[NSEG3], smax[NSEG3], smask;
    __shared__ float lut[NOBJ];

    const int b = blockIdx.y, x = blockIdx.x, tid = threadIdx.x;
    if (tid == 0) lmask = 0u;
    for (int j = tid; j < NSUB * NSEG3; j += 256) { lmin[j] = 0xFFFFFFFFu; lmax[j] = 0u; }
    __syncthreads();

    const int sub = tid & (NSUB - 1);
    const float fb = (float)(b * NOBJ);
    const int4*   tag4 = (const int4*)(tag + (size_t)b * NP);
    const float4* pc4  = (const float4*)(pc + (size_t)b * NP * 3);
    f32x4* out4 = (f32x4*)(out + 2304 + (size_t)b * NP);  // 2304 floats = keypoints
    unsigned m = 0u;
    #pragma unroll 2
    for (int i = x * 256 + tid; i < NP / 4; i += GX * 256) {
        int4 t = tag4[i];
        float4 f0 = pc4[i * 3 + 0];  // x0 y0 z0 x1
        float4 f1 = pc4[i * 3 + 1];  // y1 z1 x2 y2
        float4 f2 = pc4[i * 3 + 2];  // z2 x3 y3 z3
        f32x4 ob = {fb + (float)t.x, fb + (float)t.y, fb + (float)t.z, fb + (float)t.w};
        __builtin_nontemporal_store(ob, &out4[i]);
        m |= (1u << t.x) | (1u << t.y) | (1u << t.z) | (1u << t.w);
        // idx = (t*3+c)*16 + sub = t*48 + c*16 + sub -> bank s + 16*((t+c)&1)
        int a0 = t.x * 48 + sub, a1 = t.y * 48 + sub, a2 = t.z * 48 + sub, a3 = t.w * 48 + sub;
        unsigned k;
        k = fkey(f0.x); atomicMin(&lmin[a0 +  0], k); atomicMax(&lmax[a0 +  0], k);
        k = fkey(f0.y); atomicMin(&lmin[a0 + 16], k); atomicMax(&lmax[a0 + 16], k);
        k = fkey(f0.z); atomicMin(&lmin[a0 + 32], k); atomicMax(&lmax[a0 + 32], k);
        k = fkey(f0.w); atomicMin(&lmin[a1 +  0], k); atomicMax(&lmax[a1 +  0], k);
        k = fkey(f1.x); atomicMin(&lmin[a1 + 16], k); atomicMax(&lmax[a1 + 16], k);
        k = fkey(f1.y); atomicMin(&lmin[a1 + 32], k); atomicMax(&lmax[a1 + 32], k);
        k = fkey(f1.z); atomicMin(&lmin[a2 +  0], k); atomicMax(&lmax[a2 +  0], k);
        k = fkey(f1.w); atomicMin(&lmin[a2 + 16], k); atomicMax(&lmax[a2 + 16], k);
        k = fkey(f2.x); atomicMin(&lmin[a2 + 32], k); atomicMax(&lmax[a2 + 32], k);
        k = fkey(f2.y); atomicMin(&lmin[a3 +  0], k); atomicMax(&lmax[a3 +  0], k);
        k = fkey(f2.z); atomicMin(&lmin[a3 + 16], k); atomicMax(&lmax[a3 + 16], k);
        k = fkey(f2.w); atomicMin(&lmin[a3 + 32], k); atomicMax(&lmax[a3 + 32], k);
    }
    atomicOr(&lmask, m);
    __syncthreads();

    const int slot = b * GX + x;
    if (tid < NSEG3) {
        unsigned mn = 0xFFFFFFFFu, mx = 0u;
        #pragma unroll
        for (int s = 0; s < NSUB; ++s) {
            mn = min(mn, lmin[tid * NSUB + s]);
            mx = max(mx, lmax[tid * NSUB + s]);
        }
        ws[slot * NSEG3 + tid] = mn;
        ws[WS_SMAX + slot * NSEG3 + tid] = mx;
    }
    if (tid == 0) ws[WS_SMSK + slot] = lmask;

    // ---- last-block-per-scene finisher (replaces k3 launch) ----
    __threadfence();                      // release: slot stores visible device-wide
    __syncthreads();                      // all threads' fences done
    if (tid == 0) ticket_s = atomicAdd(&ws[WS_CTR + b], 1u);
    if (tid == 1) smask = 0u;
    __syncthreads();
    if ((ticket_s & (GX - 1)) != (GX - 1)) return;   // not last: done
    __threadfence();                      // acquire: see other blocks' slots

    if (tid < NSEG3) {
        unsigned mn = 0xFFFFFFFFu;
        #pragma unroll 8
        for (int x2 = 0; x2 < GX; ++x2) mn = min(mn, ws[(b * GX + x2) * NSEG3 + tid]);
        smin[tid] = mn;
    } else if (tid >= 64 && tid < 64 + NSEG3) {
        const int e = tid - 64;
        unsigned mx = 0u;
        #pragma unroll 8
        for (int x2 = 0; x2 < GX; ++x2) mx = max(mx, ws[WS_SMAX + (b * GX + x2) * NSEG3 + e]);
        smax[e] = mx;
    } else if (tid >= 128 && tid < 192) {
        const int e = tid - 128;
        unsigned mm = ws[WS_SMSK + b * GX + e] | ws[WS_SMSK + b * GX + 64 + e];
        atomicOr(&smask, mm);
    }
    __syncthreads();
    const unsigned mask = smask;

    if (tid == 0) {
        int tag_of[NOBJ];
        int r = -1;
        for (int t = 0; t < NOBJ; ++t)
            if ((mask >> t) & 1u) { ++r; tag_of[r] = t; }
        int nd = r + 1;
        // bbox rows: [min0, max0, ...] over dense ids; empty dense ids -> 0
        float bbox[32][3];
        for (int i = 0; i < NOBJ; ++i) {
            for (int c = 0; c < 3; ++c) {
                float mn = 0.f, mx = 0.f;
                if (i < nd) {
                    int t = tag_of[i];
                    mn = keyf(smin[t * 3 + c]);
                    mx = keyf(smax[t * 3 + c]);
                }
                bbox[2 * i][c] = mn;
                bbox[2 * i + 1][c] = mx;
            }
        }
        float* ob = out + (size_t)b * 48 * 3;
        for (int j = 0; j < 32; ++j)
            for (int c = 0; c < 3; ++c)
                ob[j * 3 + c] = bbox[j][c];
        // faithful torch barycenter: row-major split of interleaved bbox rows
        for (int j = 0; j < 16; ++j)
            for (int c = 0; c < 3; ++c)
                ob[(32 + j) * 3 + c] = 0.5f * (bbox[j][c] + bbox[16 + j][c]);
    }

    if (mask != 0xFFFFu) {  // rare, input-determined -> deterministic; block-uniform
        if (tid < NOBJ)
            lut[tid] = (float)(__popc(mask & ((2u << tid) - 1u)) - 1 + b * NOBJ);
        __syncthreads();
        const float fb2 = (float)(b * NOBJ);
        float4* o4 = (float4*)(out + 2304 + (size_t)b * NP);
        for (int i = tid; i < NP / 4; i += 256) {
            float4 v = o4[i];
            o4[i] = make_float4(lut[(int)(v.x - fb2)], lut[(int)(v.y - fb2)],
                                lut[(int)(v.z - fb2)], lut[(int)(v.w - fb2)]);
        }
    }
}

extern "C" void kernel_launch(void* const* d_in, const int* in_sizes, int n_in,
                              void* d_out, int out_size, void* d_ws, size_t ws_size,
                              hipStream_t stream) {
    const float* pc  = (const float*)d_in[0];
    const int*   tag = (const int*)d_in[1];
    float* out = (float*)d_out;
    unsigned* ws = (unsigned*)d_ws;

    kmain<<<dim3(GX, BS), 256, 0, stream>>>(pc, tag, ws, out);
}

// Round 7
// 39.973 us; speedup vs baseline: 5.7214x; 5.7214x over previous
//
#include <hip/hip_runtime.h>

#define BS 16
#define NP 500000
#define NQ (NP / 4)     // 125000 quads per scene
#define NOBJ 16
#define NSEG3 48        // NOBJ*3
#define GX 128          // blocks per scene, main kernel
#define NSUB 16         // LDS sub-tables, selected by lane&15

typedef float f32x4 __attribute__((ext_vector_type(4)));  // native vec for nontemporal store

// ws word layout (all slots written unconditionally every call -> no init pass):
//   slotmin : [0, 98304)         BS*GX*48   per-block min keys
//   slotmax : [98304, 196608)               per-block max keys
//   slotmask: [196608, 198656)   BS*GX      per-block presence bitmask
#define WS_SMAX 98304
#define WS_SMSK 196608

// Order-preserving float -> uint key (min/max over keys == min/max over floats)
__device__ __forceinline__ unsigned fkey(float f) {
    unsigned u = __float_as_uint(f);
    return (u & 0x80000000u) ? ~u : (u | 0x80000000u);
}
__device__ __forceinline__ float keyf(unsigned k) {
    unsigned u = (k & 0x80000000u) ? (k ^ 0x80000000u) : ~k;
    return __uint_as_float(u);
}

// Main fused pass: read pc+tag once; speculative obj_batch = tag + b*16;
// per-block bbox partials via LDS atomics (16 sub-tables by lane&15, ~2 lanes/bank).
// Software-pipelined: iteration n+1's global loads are issued BEFORE iteration n's
// 24 DS atomics, so HBM latency hides under the DS phase (loop is only ~4 iters).
__global__ __launch_bounds__(256) void kmain(const float* __restrict__ pc,
                                             const int* __restrict__ tag,
                                             unsigned* __restrict__ ws,
                                             float* __restrict__ out) {
    __shared__ unsigned lmin[NSUB * NSEG3], lmax[NSUB * NSEG3];
    __shared__ unsigned lmask;
    const int b = blockIdx.y, x = blockIdx.x, tid = threadIdx.x;
    if (tid == 0) lmask = 0u;
    for (int j = tid; j < NSUB * NSEG3; j += 256) { lmin[j] = 0xFFFFFFFFu; lmax[j] = 0u; }
    __syncthreads();

    const int sub = tid & (NSUB - 1);
    const float fb = (float)(b * NOBJ);
    const int4*   tag4 = (const int4*)(tag + (size_t)b * NP);
    const float4* pc4  = (const float4*)(pc + (size_t)b * NP * 3);
    f32x4* out4 = (f32x4*)(out + 2304 + (size_t)b * NP);  // 2304 floats = keypoints
    unsigned m = 0u;

    int i = x * 256 + tid;
    if (i < NQ) {
        int4   t  = tag4[i];
        float4 f0 = pc4[i * 3 + 0];  // x0 y0 z0 x1
        float4 f1 = pc4[i * 3 + 1];  // y1 z1 x2 y2
        float4 f2 = pc4[i * 3 + 2];  // z2 x3 y3 z3
        for (;;) {
            const int  ni   = i + GX * 256;
            const bool more = (ni < NQ);
            const int  li   = more ? ni : i;   // tail: re-read current (L1 hit)
            int4   nt  = tag4[li];
            float4 nf0 = pc4[li * 3 + 0];
            float4 nf1 = pc4[li * 3 + 1];
            float4 nf2 = pc4[li * 3 + 2];

            f32x4 ob = {fb + (float)t.x, fb + (float)t.y, fb + (float)t.z, fb + (float)t.w};
            __builtin_nontemporal_store(ob, &out4[i]);
            m |= (1u << t.x) | (1u << t.y) | (1u << t.z) | (1u << t.w);
            // idx = (t*3+c)*16 + sub = t*48 + c*16 + sub -> bank s + 16*((t+c)&1)
            int a0 = t.x * 48 + sub, a1 = t.y * 48 + sub, a2 = t.z * 48 + sub, a3 = t.w * 48 + sub;
            unsigned k;
            k = fkey(f0.x); atomicMin(&lmin[a0 +  0], k); atomicMax(&lmax[a0 +  0], k);
            k = fkey(f0.y); atomicMin(&lmin[a0 + 16], k); atomicMax(&lmax[a0 + 16], k);
            k = fkey(f0.z); atomicMin(&lmin[a0 + 32], k); atomicMax(&lmax[a0 + 32], k);
            k = fkey(f0.w); atomicMin(&lmin[a1 +  0], k); atomicMax(&lmax[a1 +  0], k);
            k = fkey(f1.x); atomicMin(&lmin[a1 + 16], k); atomicMax(&lmax[a1 + 16], k);
            k = fkey(f1.y); atomicMin(&lmin[a1 + 32], k); atomicMax(&lmax[a1 + 32], k);
            k = fkey(f1.z); atomicMin(&lmin[a2 +  0], k); atomicMax(&lmax[a2 +  0], k);
            k = fkey(f1.w); atomicMin(&lmin[a2 + 16], k); atomicMax(&lmax[a2 + 16], k);
            k = fkey(f2.x); atomicMin(&lmin[a2 + 32], k); atomicMax(&lmax[a2 + 32], k);
            k = fkey(f2.y); atomicMin(&lmin[a3 +  0], k); atomicMax(&lmax[a3 +  0], k);
            k = fkey(f2.z); atomicMin(&lmin[a3 + 16], k); atomicMax(&lmax[a3 + 16], k);
            k = fkey(f2.w); atomicMin(&lmin[a3 + 32], k); atomicMax(&lmax[a3 + 32], k);

            if (!more) break;
            i = ni; t = nt; f0 = nf0; f1 = nf1; f2 = nf2;
        }
    }
    atomicOr(&lmask, m);
    __syncthreads();

    const int slot = b * GX + x;
    if (tid < NSEG3) {
        unsigned mn = 0xFFFFFFFFu, mx = 0u;
        #pragma unroll
        for (int s = 0; s < NSUB; ++s) {
            mn = min(mn, lmin[tid * NSUB + s]);
            mx = max(mx, lmax[tid * NSUB + s]);
        }
        ws[slot * NSEG3 + tid] = mn;
        ws[WS_SMAX + slot * NSEG3 + tid] = mx;
    }
    if (tid == 0) ws[WS_SMSK + slot] = lmask;
}

// K3: per-scene reduction of block partials + keypoints epilogue.
// Rare path (some tag absent -> relabel not identity): rewrite scene's obj_batch.
__global__ __launch_bounds__(256) void k3(const unsigned* __restrict__ ws,
                                          float* __restrict__ out) {
    __shared__ unsigned smin[NSEG3], smax[NSEG3];
    __shared__ unsigned smask;
    __shared__ float lut[NOBJ];
    const int b = blockIdx.x, tid = threadIdx.x;

    if (tid < NSEG3) {
        unsigned mn = 0xFFFFFFFFu;
        #pragma unroll 8
        for (int x = 0; x < GX; ++x) mn = min(mn, ws[(b * GX + x) * NSEG3 + tid]);
        smin[tid] = mn;
    } else if (tid >= 64 && tid < 64 + NSEG3) {
        const int e = tid - 64;
        unsigned mx = 0u;
        #pragma unroll 8
        for (int x = 0; x < GX; ++x) mx = max(mx, ws[WS_SMAX + (b * GX + x) * NSEG3 + e]);
        smax[e] = mx;
    } else if (tid == 128) {
        unsigned mm = 0u;
        #pragma unroll 8
        for (int x = 0; x < GX; ++x) mm |= ws[WS_SMSK + b * GX + x];
        smask = mm;
    }
    __syncthreads();
    const unsigned mask = smask;

    if (tid == 0) {
        int tag_of[NOBJ];
        int r = -1;
        for (int t = 0; t < NOBJ; ++t)
            if ((mask >> t) & 1u) { ++r; tag_of[r] = t; }
        int nd = r + 1;
        // bbox rows: [min0, max0, ...] over dense ids; empty dense ids -> 0
        float bbox[32][3];
        for (int i = 0; i < NOBJ; ++i) {
            for (int c = 0; c < 3; ++c) {
                float mn = 0.f, mx = 0.f;
                if (i < nd) {
                    int t = tag_of[i];
                    mn = keyf(smin[t * 3 + c]);
                    mx = keyf(smax[t * 3 + c]);
                }
                bbox[2 * i][c] = mn;
                bbox[2 * i + 1][c] = mx;
            }
        }
        float* ob = out + (size_t)b * 48 * 3;
        for (int j = 0; j < 32; ++j)
            for (int c = 0; c < 3; ++c)
                ob[j * 3 + c] = bbox[j][c];
        // faithful torch barycenter: row-major split of interleaved bbox rows
        for (int j = 0; j < 16; ++j)
            for (int c = 0; c < 3; ++c)
                ob[(32 + j) * 3 + c] = 0.5f * (bbox[j][c] + bbox[16 + j][c]);
    }

    if (mask != 0xFFFFu) {  // rare, input-determined -> deterministic; block-uniform
        if (tid < NOBJ)
            lut[tid] = (float)(__popc(mask & ((2u << tid) - 1u)) - 1 + b * NOBJ);
        __syncthreads();
        const float fb = (float)(b * NOBJ);
        float4* out4 = (float4*)(out + 2304 + (size_t)b * NP);
        for (int i = tid; i < NP / 4; i += 256) {
            float4 v = out4[i];
            out4[i] = make_float4(lut[(int)(v.x - fb)], lut[(int)(v.y - fb)],
                                  lut[(int)(v.z - fb)], lut[(int)(v.w - fb)]);
        }
    }
}

extern "C" void kernel_launch(void* const* d_in, const int* in_sizes, int n_in,
                              void* d_out, int out_size, void* d_ws, size_t ws_size,
                              hipStream_t stream) {
    const float* pc  = (const float*)d_in[0];
    const int*   tag = (const int*)d_in[1];
    float* out = (float*)d_out;
    unsigned* ws = (unsigned*)d_ws;

    kmain<<<dim3(GX, BS), 256, 0, stream>>>(pc, tag, ws, out);
    k3<<<BS, 256, 0, stream>>>(ws, out);
}

// Round 9
// 39.304 us; speedup vs baseline: 5.8189x; 1.0170x over previous
//
#include <hip/hip_runtime.h>

#define BS 16
#define NP 500000
#define NQ (NP / 4)     // 125000 quads per scene
#define NOBJ 16
#define NSEG3 48        // NOBJ*3
#define GX 128          // blocks per scene, main kernel
#define NSUB 16         // LDS sub-tables, selected by lane&15

typedef float f32x4 __attribute__((ext_vector_type(4)));  // native vec for nontemporal store

// ws word layout (all slots written unconditionally every call -> no init pass):
//   slotmin : [0, 98304)         BS*GX*48   per-block min keys
//   slotmax : [98304, 196608)               per-block max keys
//   slotmask: [196608, 198656)   BS*GX      per-block presence bitmask
#define WS_SMAX 98304
#define WS_SMSK 196608

// Order-preserving float -> uint key (min/max over keys == min/max over floats)
__device__ __forceinline__ unsigned fkey(float f) {
    unsigned u = __float_as_uint(f);
    return (u & 0x80000000u) ? ~u : (u | 0x80000000u);
}
__device__ __forceinline__ float keyf(unsigned k) {
    unsigned u = (k & 0x80000000u) ? (k ^ 0x80000000u) : ~k;
    return __uint_as_float(u);
}

// Main fused pass (proven 39.9 µs R5 version, unchanged): read pc+tag once;
// speculative obj_batch = tag + b*16; per-block bbox partials via LDS atomics
// (16 sub-tables by lane&15: idx = t*48 + c*16 + sub -> ~2 lanes/bank, free).
__global__ __launch_bounds__(256) void kmain(const float* __restrict__ pc,
                                             const int* __restrict__ tag,
                                             unsigned* __restrict__ ws,
                                             float* __restrict__ out) {
    __shared__ unsigned lmin[NSUB * NSEG3], lmax[NSUB * NSEG3];
    __shared__ unsigned lmask;
    const int b = blockIdx.y, x = blockIdx.x, tid = threadIdx.x;
    if (tid == 0) lmask = 0u;
    for (int j = tid; j < NSUB * NSEG3; j += 256) { lmin[j] = 0xFFFFFFFFu; lmax[j] = 0u; }
    __syncthreads();

    const int sub = tid & (NSUB - 1);
    const float fb = (float)(b * NOBJ);
    const int4*   tag4 = (const int4*)(tag + (size_t)b * NP);
    const float4* pc4  = (const float4*)(pc + (size_t)b * NP * 3);
    f32x4* out4 = (f32x4*)(out + 2304 + (size_t)b * NP);  // 2304 floats = keypoints
    unsigned m = 0u;
    for (int i = x * 256 + tid; i < NQ; i += GX * 256) {
        int4 t = tag4[i];
        float4 f0 = pc4[i * 3 + 0];  // x0 y0 z0 x1
        float4 f1 = pc4[i * 3 + 1];  // y1 z1 x2 y2
        float4 f2 = pc4[i * 3 + 2];  // z2 x3 y3 z3
        f32x4 ob = {fb + (float)t.x, fb + (float)t.y, fb + (float)t.z, fb + (float)t.w};
        __builtin_nontemporal_store(ob, &out4[i]);
        m |= (1u << t.x) | (1u << t.y) | (1u << t.z) | (1u << t.w);
        int a0 = t.x * 48 + sub, a1 = t.y * 48 + sub, a2 = t.z * 48 + sub, a3 = t.w * 48 + sub;
        unsigned k;
        k = fkey(f0.x); atomicMin(&lmin[a0 +  0], k); atomicMax(&lmax[a0 +  0], k);
        k = fkey(f0.y); atomicMin(&lmin[a0 + 16], k); atomicMax(&lmax[a0 + 16], k);
        k = fkey(f0.z); atomicMin(&lmin[a0 + 32], k); atomicMax(&lmax[a0 + 32], k);
        k = fkey(f0.w); atomicMin(&lmin[a1 +  0], k); atomicMax(&lmax[a1 +  0], k);
        k = fkey(f1.x); atomicMin(&lmin[a1 + 16], k); atomicMax(&lmax[a1 + 16], k);
        k = fkey(f1.y); atomicMin(&lmin[a1 + 32], k); atomicMax(&lmax[a1 + 32], k);
        k = fkey(f1.z); atomicMin(&lmin[a2 +  0], k); atomicMax(&lmax[a2 +  0], k);
        k = fkey(f1.w); atomicMin(&lmin[a2 + 16], k); atomicMax(&lmax[a2 + 16], k);
        k = fkey(f2.x); atomicMin(&lmin[a2 + 32], k); atomicMax(&lmax[a2 + 32], k);
        k = fkey(f2.y); atomicMin(&lmin[a3 +  0], k); atomicMax(&lmax[a3 +  0], k);
        k = fkey(f2.z); atomicMin(&lmin[a3 + 16], k); atomicMax(&lmax[a3 + 16], k);
        k = fkey(f2.w); atomicMin(&lmin[a3 + 32], k); atomicMax(&lmax[a3 + 32], k);
    }
    atomicOr(&lmask, m);
    __syncthreads();

    const int slot = b * GX + x;
    if (tid < NSEG3) {
        unsigned mn = 0xFFFFFFFFu, mx = 0u;
        #pragma unroll
        for (int s = 0; s < NSUB; ++s) {
            mn = min(mn, lmin[tid * NSUB + s]);
            mx = max(mx, lmax[tid * NSUB + s]);
        }
        ws[slot * NSEG3 + tid] = mn;
        ws[WS_SMAX + slot * NSEG3 + tid] = mx;
    }
    if (tid == 0) ws[WS_SMSK + slot] = lmask;
}

// K3: per-scene reduction of block partials + keypoints epilogue.
// 4-wave parallel stage 1 (each wave reduces a 32-block quarter, min+max;
// lanes 56-63 OR the mask quarter), stage 2 combines 4 partials.
// Rare path (some tag absent -> relabel not identity): rewrite scene's obj_batch.
__global__ __launch_bounds__(256) void k3(const unsigned* __restrict__ ws,
                                          float* __restrict__ out) {
    __shared__ unsigned pmin[4][NSEG3], pmax[4][NSEG3];
    __shared__ unsigned smin[NSEG3], smax[NSEG3];
    __shared__ unsigned smask;
    __shared__ float lut[NOBJ];
    const int b = blockIdx.x, tid = threadIdx.x;
    const int wave = tid >> 6, lane = tid & 63;

    if (tid == 0) smask = 0u;
    __syncthreads();

    if (lane < NSEG3) {
        unsigned mn = 0xFFFFFFFFu, mx = 0u;
        const int x0 = wave * (GX / 4);
        #pragma unroll 8
        for (int x2 = x0; x2 < x0 + GX / 4; ++x2) {
            mn = min(mn, ws[(b * GX + x2) * NSEG3 + lane]);
            mx = max(mx, ws[WS_SMAX + (b * GX + x2) * NSEG3 + lane]);
        }
        pmin[wave][lane] = mn;
        pmax[wave][lane] = mx;
    } else if (lane >= 56) {
        const int base = b * GX + wave * (GX / 4) + (lane - 56) * 4;
        unsigned mm = ws[WS_SMSK + base] | ws[WS_SMSK + base + 1]
                    | ws[WS_SMSK + base + 2] | ws[WS_SMSK + base + 3];
        atomicOr(&smask, mm);
    }
    __syncthreads();

    if (tid < NSEG3)
        smin[tid] = min(min(pmin[0][tid], pmin[1][tid]), min(pmin[2][tid], pmin[3][tid]));
    else if (tid >= 64 && tid < 64 + NSEG3) {
        const int e = tid - 64;
        smax[e] = max(max(pmax[0][e], pmax[1][e]), max(pmax[2][e], pmax[3][e]));
    }
    __syncthreads();
    const unsigned mask = smask;

    if (tid == 0) {
        int tag_of[NOBJ];
        int r = -1;
        for (int t = 0; t < NOBJ; ++t)
            if ((mask >> t) & 1u) { ++r; tag_of[r] = t; }
        int nd = r + 1;
        // bbox rows: [min0, max0, ...] over dense ids; empty dense ids -> 0
        float bbox[32][3];
        for (int i = 0; i < NOBJ; ++i) {
            for (int c = 0; c < 3; ++c) {
                float mn = 0.f, mx = 0.f;
                if (i < nd) {
                    int t = tag_of[i];
                    mn = keyf(smin[t * 3 + c]);
                    mx = keyf(smax[t * 3 + c]);
                }
                bbox[2 * i][c] = mn;
                bbox[2 * i + 1][c] = mx;
            }
        }
        float* ob = out + (size_t)b * 48 * 3;
        for (int j = 0; j < 32; ++j)
            for (int c = 0; c < 3; ++c)
                ob[j * 3 + c] = bbox[j][c];
        // faithful torch barycenter: row-major split of interleaved bbox rows
        for (int j = 0; j < 16; ++j)
            for (int c = 0; c < 3; ++c)
                ob[(32 + j) * 3 + c] = 0.5f * (bbox[j][c] + bbox[16 + j][c]);
    }

    if (mask != 0xFFFFu) {  // rare, input-determined -> deterministic; block-uniform
        if (tid < NOBJ)
            lut[tid] = (float)(__popc(mask & ((2u << tid) - 1u)) - 1 + b * NOBJ);
        __syncthreads();
        const float fb = (float)(b * NOBJ);
        float4* out4 = (float4*)(out + 2304 + (size_t)b * NP);
        for (int i = tid; i < NQ; i += 256) {
            float4 v = out4[i];
            out4[i] = make_float4(lut[(int)(v.x - fb)], lut[(int)(v.y - fb)],
                                  lut[(int)(v.z - fb)], lut[(int)(v.w - fb)]);
        }
    }
}

extern "C" void kernel_launch(void* const* d_in, const int* in_sizes, int n_in,
                              void* d_out, int out_size, void* d_ws, size_t ws_size,
                              hipStream_t stream) {
    const float* pc  = (const float*)d_in[0];
    const int*   tag = (const int*)d_in[1];
    float* out = (float*)d_out;
    unsigned* ws = (unsigned*)d_ws;

    kmain<<<dim3(GX, BS), 256, 0, stream>>>(pc, tag, ws, out);
    k3<<<BS, 256, 0, stream>>>(ws, out);
}